// Round 15
// baseline (13587.875 us; speedup 1.0000x reference)
//
#include <hip/hip_runtime.h>
#include <hip/hip_bf16.h>
#include <float.h>
#include <math.h>

#define NB 4
#define NN 8192
#define FF 64
#define MM 2048
#define KK 32
#define HH 64

#define FB 4            // fps blocks (slices) per cloud
#define FTH 512         // threads per fps block (8 waves)
#define SPT 4           // slice points per thread (2048/512)
#define LSTRIDE 16      // sync line stride in u64 units (128 B)

typedef unsigned long long u64;

// DPP float-max step (old = -inf identity), validated r4/r11/r13.
#define DPP_FMAX(v, ctrl, rmask)                                                \
    { int _t = __builtin_amdgcn_update_dpp((int)0xff800000, __float_as_int(v),  \
                   (ctrl), (rmask), 0xf, false);                                \
      (v) = fmaxf((v), __int_as_float(_t)); }
#define DPP_FMAX6(v)  DPP_FMAX(v,0x111,0xf) DPP_FMAX(v,0x112,0xf) \
                      DPP_FMAX(v,0x114,0xf) DPP_FMAX(v,0x118,0xf) \
                      DPP_FMAX(v,0x142,0xa) DPP_FMAX(v,0x143,0xc)

// DPP int-min step (old = INT_MAX identity), validated r11/r13.
#define DPP_IMIN(v, ctrl, rmask)                                                \
    { int _t = __builtin_amdgcn_update_dpp((int)0x7fffffff, (v),                \
                   (ctrl), (rmask), 0xf, false);                                \
      (v) = min((v), _t); }
#define DPP_IMIN6(v)  DPP_IMIN(v,0x111,0xf) DPP_IMIN(v,0x112,0xf) \
                      DPP_IMIN(v,0x114,0xf) DPP_IMIN(v,0x118,0xf) \
                      DPP_IMIN(v,0x142,0xa) DPP_IMIN(v,0x143,0xc)

__device__ __forceinline__ float readlane_f(float v, int l) {
    return __int_as_float(__builtin_amdgcn_readlane(__float_as_int(v), l));
}

// ---------------- init: zero padded sync lines (replay-safe) ----------------
__global__ void zero_sync_kernel(u64* __restrict__ syncW) {
    const int n = NB * FB * 2 * LSTRIDE;           // 512 u64 = 4 KB
    if (threadIdx.x < n) syncW[threadIdx.x] = 0ull;
}

// ------- Kernel 1: exact FPS, 4 same-XCD blocks per cloud, L2 handshake -------
__global__ __launch_bounds__(FTH) void fps_kernel(
    const float* __restrict__ pos,
    u64* __restrict__ syncW,
    int* __restrict__ samp,
    float* __restrict__ centers_out,
    float* __restrict__ batch_out)
{
#pragma clang fp contract(off)
    __shared__ float4 pts4[NN];          // full cloud, natural order (128 KB)
    __shared__ u64 wslot[2][8];          // parity-buffered per-wave packed keys

    const int bid = blockIdx.x;
    const int cloud = bid & 7;           // bid%8 -> same XCD for all 4 slices
    if (cloud >= NB) return;             // 16 of 32 blocks are placeholders
    const int slice = bid >> 3;          // 0..3
    const float* pb = pos + (size_t)cloud * NN * 3;
    const int tid = threadIdx.x;
    const int w   = tid >> 6;
    const int lane = tid & 63;
    const int base = slice * (NN / FB);  // my slice's first point

    // per-cloud sync lines: line (slice*2+par), each 128 B apart
    u64* W = syncW + (size_t)cloud * (FB * 2 * LSTRIDE);

    // ---- stage full cloud (winner fetch needs any point) ----
    for (int j = tid; j < NN; j += FTH)
        pts4[j] = make_float4(pb[j * 3 + 0], pb[j * 3 + 1], pb[j * 3 + 2], 0.0f);
    if (slice == 0)
        for (int j = tid; j < MM; j += FTH) batch_out[cloud * MM + j] = (float)cloud;
    __syncthreads();

    // ---- my 4 slice points in registers ----
    float px[SPT], py[SPT], pz[SPT], dist[SPT];
#pragma unroll
    for (int i = 0; i < SPT; ++i) {
        const float4 p = pts4[base + i * FTH + tid];
        px[i] = p.x; py[i] = p.y; pz[i] = p.z;
        dist[i] = INFINITY;
    }

    int   cur = 0;
    float lx = pts4[0].x, ly = pts4[0].y, lz = pts4[0].z;

    for (int s = 0; s < MM; ++s) {
#pragma clang fp contract(off)
        if (slice == 0 && tid == 0) {
            samp[cloud * MM + s] = cur;
            centers_out[((size_t)cloud * MM + s) * 3 + 0] = lx;
            centers_out[((size_t)cloud * MM + s) * 3 + 1] = ly;
            centers_out[((size_t)cloud * MM + s) * 3 + 2] = lz;
        }
        if (s == MM - 1) break;   // last argmax unused by the reference

        const int par = s & 1;

        // ---- local update: 4 points, exact ref arithmetic ----
#pragma unroll
        for (int i = 0; i < SPT; ++i) {
            const float dx = __fsub_rn(px[i], lx);
            const float dy = __fsub_rn(py[i], ly);
            const float dz = __fsub_rn(pz[i], lz);
            const float d  = __fadd_rn(__fadd_rn(__fmul_rn(dx, dx),
                                                 __fmul_rn(dy, dy)),
                                       __fmul_rn(dz, dz));
            dist[i] = fminf(dist[i], d);
        }
        const float tv = fmaxf(fmaxf(dist[0], dist[1]), fmaxf(dist[2], dist[3]));

        // ---- wave value max -> broadcast; sparse lowest-index recovery ----
        float wv = tv;
        DPP_FMAX6(wv)
        const float wmax = readlane_f(wv, 63);

        int cand = 0x7fffffff;
        if (tv == wmax) {
            // descending global-index order keeps lowest match (ref tie-break)
#pragma unroll
            for (int i = SPT - 1; i >= 0; --i)
                cand = (dist[i] == wmax) ? base + i * FTH + tid : cand;
        }
        DPP_IMIN6(cand)

        // ---- per-wave packed key, one barrier, u64-max tree -> block key ----
        if (lane == 63)
            wslot[par][w] = (((u64)(unsigned int)__float_as_int(wmax)) << 32)
                          | (((u64)(unsigned int)(8191 - cand)) << 16);
        __syncthreads();

        const u64 k0 = wslot[par][0], k1 = wslot[par][1];
        const u64 k2 = wslot[par][2], k3 = wslot[par][3];
        const u64 k4 = wslot[par][4], k5 = wslot[par][5];
        const u64 k6 = wslot[par][6], k7 = wslot[par][7];
        u64 bb = k0 > k1 ? k0 : k1;
        { const u64 t = k2 > k3 ? k2 : k3; if (t > bb) bb = t; }
        { const u64 t = k4 > k5 ? k4 : k5; if (t > bb) bb = t; }
        { const u64 t = k6 > k7 ? k6 : k7; if (t > bb) bb = t; }
        bb |= (u64)(s + 1);   // step tag in low 16 bits

        // ---- publish (own 128B line) + spin on 3 same-XCD peers ----
        if (tid == 0) atomicExch(&W[(slice * 2 + par) * LSTRIDE], bb);

        u64 fin = bb;
#pragma unroll
        for (int p = 0; p < FB; ++p) {
            if (p == slice) continue;
            const u64* addr = &W[(p * 2 + par) * LSTRIDE];
            u64 v;
            do {
                v = __hip_atomic_load(addr, __ATOMIC_ACQUIRE,
                                      __HIP_MEMORY_SCOPE_AGENT);
            } while ((v & 0xFFFFull) != (u64)(s + 1));
            if (v > fin) fin = v;
        }

        cur = 8191 - (int)((fin >> 16) & 0x1FFFull);
        const float4 wp = pts4[cur];               // LDS broadcast, conflict-free
        lx = wp.x; ly = wp.y; lz = wp.z;
    }
}

// ---------------- Kernel 2: radius-KNN, one wave per center ----------------
#define CAP 256
__global__ __launch_bounds__(256) void knn_kernel(
    const float* __restrict__ pos,
    const int* __restrict__ samp,
    int* __restrict__ nbr,
    int* __restrict__ cntbuf)
{
    const int wave = threadIdx.x >> 6;
    const int lane = threadIdx.x & 63;
    const int c = blockIdx.x * 4 + wave;
    const int b = c >> 11;
    const float* pb = pos + (size_t)b * NN * 3;

    __shared__ float sd2[4][CAP];
    __shared__ int   sid[4][CAP];

    const int ctr = samp[c];
    const float cx = pb[ctr * 3 + 0];
    const float cy = pb[ctr * 3 + 1];
    const float cz = pb[ctr * 3 + 2];
    const float R2 = (float)(0.1 * 0.1);

    int cnt = 0;
    for (int r = 0; r < NN / 64; ++r) {
        const int g = r * 64 + lane;
        float dx = __fsub_rn(cx, pb[g * 3 + 0]);
        float dy = __fsub_rn(cy, pb[g * 3 + 1]);
        float dz = __fsub_rn(cz, pb[g * 3 + 2]);
        float d2 = __fadd_rn(__fadd_rn(__fmul_rn(dx, dx), __fmul_rn(dy, dy)),
                             __fmul_rn(dz, dz));
        const bool pred = (d2 <= R2);
        const unsigned long long mask = __ballot(pred);
        const int before = __popcll(mask & ((1ull << lane) - 1ull));
        if (pred) {
            const int slot = cnt + before;
            if (slot < CAP) { sd2[wave][slot] = d2; sid[wave][slot] = g; }
        }
        cnt += __popcll(mask);
    }
    if (cnt > CAP) cnt = CAP;
    __syncthreads();

    for (int ci = lane; ci < cnt; ci += 64) {
        const float dc = sd2[wave][ci];
        const int   ic = sid[wave][ci];
        int rank = 0;
        for (int j = 0; j < cnt; ++j) {
            const float dj = sd2[wave][j];
            const int   ij = sid[wave][j];
            rank += (dj < dc || (dj == dc && ij < ic)) ? 1 : 0;
        }
        if (rank < KK) nbr[c * KK + rank] = ic;
    }
    if (lane == 0) cntbuf[c] = (cnt < KK) ? cnt : KK;
}

// ---------------- Kernel 3: gather + MLP + max-pool, one wave per center ----
__global__ __launch_bounds__(256) void mlp_kernel(
    const float* __restrict__ x,
    const float* __restrict__ pos,
    const float* __restrict__ W1,
    const float* __restrict__ b1,
    const float* __restrict__ W2,
    const float* __restrict__ b2,
    const int* __restrict__ nbr,
    const int* __restrict__ cntbuf,
    const float* __restrict__ centers,
    float* __restrict__ out)
{
    __shared__ float WT[64 * 68];
    __shared__ float featL[4][32 * 68];

    const int tid = threadIdx.x, wave = tid >> 6, lane = tid & 63;
    const int c = blockIdx.x * 4 + wave;
    const int b = c >> 11;
    const int cnt = cntbuf[c];

    for (int idx = tid; idx < 67 * 64; idx += 256) {
        const int i = idx >> 6, h = idx & 63;
        WT[h * 68 + i] = W1[idx];
    }
    if (tid < 64) WT[tid * 68 + 67] = 0.0f;

    const float ctr0 = centers[c * 3 + 0];
    const float ctr1 = centers[c * 3 + 1];
    const float ctr2 = centers[c * 3 + 2];
    for (int k = 0; k < cnt; ++k) {
        const int j = nbr[c * KK + k];
        featL[wave][k * 68 + lane] = x[((size_t)b * NN + j) * FF + lane];
        if (lane < 3) {
            const float pj = pos[((size_t)b * NN + j) * 3 + lane];
            const float ci = (lane == 0) ? ctr0 : ((lane == 1) ? ctr1 : ctr2);
            featL[wave][k * 68 + 64 + lane] = __fsub_rn(pj, ci);
        }
        if (lane == 3) featL[wave][k * 68 + 67] = 0.0f;
    }
    __syncthreads();

    float wreg[68];
#pragma unroll
    for (int i4 = 0; i4 < 17; ++i4) {
        const float4 v = *(const float4*)&WT[lane * 68 + i4 * 4];
        wreg[i4 * 4 + 0] = v.x; wreg[i4 * 4 + 1] = v.y;
        wreg[i4 * 4 + 2] = v.z; wreg[i4 * 4 + 3] = v.w;
    }
    const float bias1 = b1[lane];
    for (int k = 0; k < cnt; ++k) {
        float acc = bias1;
#pragma unroll
        for (int i4 = 0; i4 < 17; ++i4) {
            const float4 f = *(const float4*)&featL[wave][k * 68 + i4 * 4];
            acc = fmaf(f.x, wreg[i4 * 4 + 0], acc);
            acc = fmaf(f.y, wreg[i4 * 4 + 1], acc);
            acc = fmaf(f.z, wreg[i4 * 4 + 2], acc);
            acc = fmaf(f.w, wreg[i4 * 4 + 3], acc);
        }
        featL[wave][k * 68 + lane] = fmaxf(acc, 0.0f);
    }
    __syncthreads();

    for (int idx = tid; idx < 64 * 64; idx += 256) {
        const int i = idx >> 6, h = idx & 63;
        WT[h * 68 + i] = W2[idx];
    }
    __syncthreads();

#pragma unroll
    for (int i4 = 0; i4 < 16; ++i4) {
        const float4 v = *(const float4*)&WT[lane * 68 + i4 * 4];
        wreg[i4 * 4 + 0] = v.x; wreg[i4 * 4 + 1] = v.y;
        wreg[i4 * 4 + 2] = v.z; wreg[i4 * 4 + 3] = v.w;
    }
    const float bias2 = b2[lane];
    float m = -INFINITY;
    for (int k = 0; k < cnt; ++k) {
        float acc = bias2;
#pragma unroll
        for (int i4 = 0; i4 < 16; ++i4) {
            const float4 f = *(const float4*)&featL[wave][k * 68 + i4 * 4];
            acc = fmaf(f.x, wreg[i4 * 4 + 0], acc);
            acc = fmaf(f.y, wreg[i4 * 4 + 1], acc);
            acc = fmaf(f.z, wreg[i4 * 4 + 2], acc);
            acc = fmaf(f.w, wreg[i4 * 4 + 3], acc);
        }
        m = fmaxf(m, fmaxf(acc, 0.0f));
    }
    out[(size_t)c * HH + lane] = (cnt > 0) ? m : 0.0f;
}

extern "C" void kernel_launch(void* const* d_in, const int* in_sizes, int n_in,
                              void* d_out, int out_size, void* d_ws, size_t ws_size,
                              hipStream_t stream) {
    const float* x   = (const float*)d_in[0];
    const float* pos = (const float*)d_in[1];
    const float* W1  = (const float*)d_in[3];
    const float* b1  = (const float*)d_in[4];
    const float* W2  = (const float*)d_in[5];
    const float* b2  = (const float*)d_in[6];

    float* out         = (float*)d_out;
    float* centers_out = out + (size_t)NB * MM * HH;
    float* batch_out   = centers_out + (size_t)NB * MM * 3;

    char* ws = (char*)d_ws;
    int* samp   = (int*)ws;                                   // 32 KB
    int* cntbuf = (int*)(ws + (size_t)NB * MM * 4);           // 32 KB
    int* nbr    = (int*)(ws + (size_t)2 * NB * MM * 4);       // 1 MB
    u64* syncW  = (u64*)(ws + (size_t)2 * NB * MM * 4
                            + (size_t)NB * MM * KK * 4);      // 4 KB padded lines

    zero_sync_kernel<<<1, 512, 0, stream>>>(syncW);
    fps_kernel<<<32, FTH, 0, stream>>>(pos, syncW, samp, centers_out, batch_out);
    knn_kernel<<<(NB * MM) / 4, 256, 0, stream>>>(pos, samp, nbr, cntbuf);
    mlp_kernel<<<(NB * MM) / 4, 256, 0, stream>>>(x, pos, W1, b1, W2, b2,
                                                  nbr, cntbuf, centers_out, out);
}

// Round 16
// 2476.317 us; speedup vs baseline: 5.4871x; 5.4871x over previous
//
#include <hip/hip_runtime.h>
#include <hip/hip_bf16.h>
#include <float.h>
#include <math.h>

#define NB 4
#define NN 8192
#define FF 64
#define MM 2048
#define KK 32
#define HH 64

#define FT 1024         // fps threads (16 waves, 4 per SIMD)
#define NPAIR 4         // 8 points per thread = 4 packed pairs

typedef float v2f __attribute__((ext_vector_type(2)));

// DPP float-max step (old = -inf identity), validated r4/r11/r13.
#define DPP_FMAX(v, ctrl, rmask)                                                \
    { int _t = __builtin_amdgcn_update_dpp((int)0xff800000, __float_as_int(v),  \
                   (ctrl), (rmask), 0xf, false);                                \
      (v) = fmaxf((v), __int_as_float(_t)); }
#define DPP_FMAX6(v)  DPP_FMAX(v,0x111,0xf) DPP_FMAX(v,0x112,0xf) \
                      DPP_FMAX(v,0x114,0xf) DPP_FMAX(v,0x118,0xf) \
                      DPP_FMAX(v,0x142,0xa) DPP_FMAX(v,0x143,0xc)

// DPP int-min step (old = INT_MAX identity), validated r11/r13.
#define DPP_IMIN(v, ctrl, rmask)                                                \
    { int _t = __builtin_amdgcn_update_dpp((int)0x7fffffff, (v),                \
                   (ctrl), (rmask), 0xf, false);                                \
      (v) = min((v), _t); }
#define DPP_IMIN6(v)  DPP_IMIN(v,0x111,0xf) DPP_IMIN(v,0x112,0xf) \
                      DPP_IMIN(v,0x114,0xf) DPP_IMIN(v,0x118,0xf) \
                      DPP_IMIN(v,0x142,0xa) DPP_IMIN(v,0x143,0xc)

// ---------------- Kernel 1: exact FPS, r11 structure at 16 waves ----------------
__global__ __launch_bounds__(FT) void fps_kernel(
    const float* __restrict__ pos,
    int* __restrict__ samp,
    float* __restrict__ centers_out,
    float* __restrict__ batch_out)
{
#pragma clang fp contract(off)
    __shared__ float4 pts4[NN];          // natural order; winner-fetch only (128 KB)
    __shared__ float vslot[2][16];       // parity per-wave value maxes
    __shared__ int   islot[2][16];       // parity per-wave min matching idx

    const int b = blockIdx.x;
    const float* pb = pos + (size_t)b * NN * 3;
    const int tid = threadIdx.x;
    const int w   = tid >> 6;
    const int lane = tid & 63;

    // ---- stage points; prefill batch ids ----
    for (int j = tid; j < NN; j += FT)
        pts4[j] = make_float4(pb[j * 3 + 0], pb[j * 3 + 1], pb[j * 3 + 2], 0.0f);
    for (int j = tid; j < MM; j += FT) batch_out[b * MM + j] = (float)b;
    __syncthreads();

    // ---- 8 points/thread as 4 packed pairs (r11 layout, half depth) ----
    // pair j: indices (2j)*FT+tid (.x) and (2j+1)*FT+tid (.y)
    v2f pxv[NPAIR], pyv[NPAIR], pzv[NPAIR], dv[NPAIR];
#pragma unroll
    for (int j = 0; j < NPAIR; ++j) {
        const float4 p0 = pts4[(2 * j) * FT + tid];
        const float4 p1 = pts4[(2 * j + 1) * FT + tid];
        pxv[j] = (v2f){p0.x, p1.x};
        pyv[j] = (v2f){p0.y, p1.y};
        pzv[j] = (v2f){p0.z, p1.z};
        dv[j]  = (v2f){INFINITY, INFINITY};
    }

    int   cur = 0;
    float lx = pb[0], ly = pb[1], lz = pb[2];

    for (int s = 0; s < MM; ++s) {
#pragma clang fp contract(off)
        if (tid == 0) {
            samp[b * MM + s] = cur;
            centers_out[((size_t)b * MM + s) * 3 + 0] = lx;
            centers_out[((size_t)b * MM + s) * 3 + 1] = ly;
            centers_out[((size_t)b * MM + s) * 3 + 2] = lz;
        }
        if (s == MM - 1) break;   // last argmax unused by the reference

        const v2f l2x = (v2f){lx, lx};
        const v2f l2y = (v2f){ly, ly};
        const v2f l2z = (v2f){lz, lz};

        // ---- phase 1 (r11 verbatim, 4 pairs): distance update + value max ----
        v2f vmax2 = (v2f){-INFINITY, -INFINITY};
#pragma unroll
        for (int j = 0; j < NPAIR; ++j) {
            const v2f dx = pxv[j] - l2x;
            const v2f dy = pyv[j] - l2y;
            const v2f dz = pzv[j] - l2z;
            const v2f d2 = (dx * dx + dy * dy) + dz * dz;   // exact: contract off
            dv[j] = __builtin_elementwise_min(dv[j], d2);   // jnp.minimum, exact
            vmax2 = __builtin_elementwise_max(vmax2, dv[j]);
        }
        const float tv = fmaxf(vmax2.x, vmax2.y);           // thread value max

        float wv = tv;
        DPP_FMAX6(wv)                                       // lane63: wave max
        const int par = s & 1;
        if (lane == 63) vslot[par][w] = wv;
        __syncthreads();

        // ---- block value max over 16 per-wave slots ----
        const float4 v0 = *(const float4*)&vslot[par][0];
        const float4 v1 = *(const float4*)&vslot[par][4];
        const float4 v2 = *(const float4*)&vslot[par][8];
        const float4 v3 = *(const float4*)&vslot[par][12];
        const float V = fmaxf(
            fmaxf(fmaxf(fmaxf(v0.x, v0.y), fmaxf(v0.z, v0.w)),
                  fmaxf(fmaxf(v1.x, v1.y), fmaxf(v1.z, v1.w))),
            fmaxf(fmaxf(fmaxf(v2.x, v2.y), fmaxf(v2.z, v2.w)),
                  fmaxf(fmaxf(v3.x, v3.y), fmaxf(v3.z, v3.w))));

        // ---- phase 2: rare index recovery (exec-sparse; ~1 thread/block) ----
        int cand = 0x7fffffff;
        if (tv == V) {
            // ascending index order -> branchless min keeps LOWEST match
#pragma unroll
            for (int j = 0; j < NPAIR; ++j) {
                if (dv[j].x == V) cand = min(cand, (2 * j) * FT + tid);
                if (dv[j].y == V) cand = min(cand, (2 * j + 1) * FT + tid);
            }
        }
        DPP_IMIN6(cand)                                     // lane63: wave min idx
        if (lane == 63) islot[par][w] = cand;
        __syncthreads();

        const int4 i0 = *(const int4*)&islot[par][0];
        const int4 i1 = *(const int4*)&islot[par][4];
        const int4 i2 = *(const int4*)&islot[par][8];
        const int4 i3 = *(const int4*)&islot[par][12];
        cur = min(min(min(min(i0.x, i0.y), min(i0.z, i0.w)),
                      min(min(i1.x, i1.y), min(i1.z, i1.w))),
                  min(min(min(i2.x, i2.y), min(i2.z, i2.w)),
                      min(min(i3.x, i3.y), min(i3.z, i3.w))));

        const float4 wp = pts4[cur];                        // broadcast, conflict-free
        lx = wp.x; ly = wp.y; lz = wp.z;
    }
}

// ---------------- Kernel 2: radius-KNN, one wave per center ----------------
#define CAP 256
__global__ __launch_bounds__(256) void knn_kernel(
    const float* __restrict__ pos,
    const int* __restrict__ samp,
    int* __restrict__ nbr,
    int* __restrict__ cntbuf)
{
    const int wave = threadIdx.x >> 6;
    const int lane = threadIdx.x & 63;
    const int c = blockIdx.x * 4 + wave;
    const int b = c >> 11;
    const float* pb = pos + (size_t)b * NN * 3;

    __shared__ float sd2[4][CAP];
    __shared__ int   sid[4][CAP];

    const int ctr = samp[c];
    const float cx = pb[ctr * 3 + 0];
    const float cy = pb[ctr * 3 + 1];
    const float cz = pb[ctr * 3 + 2];
    const float R2 = (float)(0.1 * 0.1);

    int cnt = 0;
    for (int r = 0; r < NN / 64; ++r) {
        const int g = r * 64 + lane;
        float dx = __fsub_rn(cx, pb[g * 3 + 0]);
        float dy = __fsub_rn(cy, pb[g * 3 + 1]);
        float dz = __fsub_rn(cz, pb[g * 3 + 2]);
        float d2 = __fadd_rn(__fadd_rn(__fmul_rn(dx, dx), __fmul_rn(dy, dy)),
                             __fmul_rn(dz, dz));
        const bool pred = (d2 <= R2);
        const unsigned long long mask = __ballot(pred);
        const int before = __popcll(mask & ((1ull << lane) - 1ull));
        if (pred) {
            const int slot = cnt + before;
            if (slot < CAP) { sd2[wave][slot] = d2; sid[wave][slot] = g; }
        }
        cnt += __popcll(mask);
    }
    if (cnt > CAP) cnt = CAP;
    __syncthreads();

    for (int ci = lane; ci < cnt; ci += 64) {
        const float dc = sd2[wave][ci];
        const int   ic = sid[wave][ci];
        int rank = 0;
        for (int j = 0; j < cnt; ++j) {
            const float dj = sd2[wave][j];
            const int   ij = sid[wave][j];
            rank += (dj < dc || (dj == dc && ij < ic)) ? 1 : 0;
        }
        if (rank < KK) nbr[c * KK + rank] = ic;
    }
    if (lane == 0) cntbuf[c] = (cnt < KK) ? cnt : KK;
}

// ---------------- Kernel 3: gather + MLP + max-pool, one wave per center ----
__global__ __launch_bounds__(256) void mlp_kernel(
    const float* __restrict__ x,
    const float* __restrict__ pos,
    const float* __restrict__ W1,
    const float* __restrict__ b1,
    const float* __restrict__ W2,
    const float* __restrict__ b2,
    const int* __restrict__ nbr,
    const int* __restrict__ cntbuf,
    const float* __restrict__ centers,
    float* __restrict__ out)
{
    __shared__ float WT[64 * 68];
    __shared__ float featL[4][32 * 68];

    const int tid = threadIdx.x, wave = tid >> 6, lane = tid & 63;
    const int c = blockIdx.x * 4 + wave;
    const int b = c >> 11;
    const int cnt = cntbuf[c];

    for (int idx = tid; idx < 67 * 64; idx += 256) {
        const int i = idx >> 6, h = idx & 63;
        WT[h * 68 + i] = W1[idx];
    }
    if (tid < 64) WT[tid * 68 + 67] = 0.0f;

    const float ctr0 = centers[c * 3 + 0];
    const float ctr1 = centers[c * 3 + 1];
    const float ctr2 = centers[c * 3 + 2];
    for (int k = 0; k < cnt; ++k) {
        const int j = nbr[c * KK + k];
        featL[wave][k * 68 + lane] = x[((size_t)b * NN + j) * FF + lane];
        if (lane < 3) {
            const float pj = pos[((size_t)b * NN + j) * 3 + lane];
            const float ci = (lane == 0) ? ctr0 : ((lane == 1) ? ctr1 : ctr2);
            featL[wave][k * 68 + 64 + lane] = __fsub_rn(pj, ci);
        }
        if (lane == 3) featL[wave][k * 68 + 67] = 0.0f;
    }
    __syncthreads();

    float wreg[68];
#pragma unroll
    for (int i4 = 0; i4 < 17; ++i4) {
        const float4 v = *(const float4*)&WT[lane * 68 + i4 * 4];
        wreg[i4 * 4 + 0] = v.x; wreg[i4 * 4 + 1] = v.y;
        wreg[i4 * 4 + 2] = v.z; wreg[i4 * 4 + 3] = v.w;
    }
    const float bias1 = b1[lane];
    for (int k = 0; k < cnt; ++k) {
        float acc = bias1;
#pragma unroll
        for (int i4 = 0; i4 < 17; ++i4) {
            const float4 f = *(const float4*)&featL[wave][k * 68 + i4 * 4];
            acc = fmaf(f.x, wreg[i4 * 4 + 0], acc);
            acc = fmaf(f.y, wreg[i4 * 4 + 1], acc);
            acc = fmaf(f.z, wreg[i4 * 4 + 2], acc);
            acc = fmaf(f.w, wreg[i4 * 4 + 3], acc);
        }
        featL[wave][k * 68 + lane] = fmaxf(acc, 0.0f);
    }
    __syncthreads();

    for (int idx = tid; idx < 64 * 64; idx += 256) {
        const int i = idx >> 6, h = idx & 63;
        WT[h * 68 + i] = W2[idx];
    }
    __syncthreads();

#pragma unroll
    for (int i4 = 0; i4 < 16; ++i4) {
        const float4 v = *(const float4*)&WT[lane * 68 + i4 * 4];
        wreg[i4 * 4 + 0] = v.x; wreg[i4 * 4 + 1] = v.y;
        wreg[i4 * 4 + 2] = v.z; wreg[i4 * 4 + 3] = v.w;
    }
    const float bias2 = b2[lane];
    float m = -INFINITY;
    for (int k = 0; k < cnt; ++k) {
        float acc = bias2;
#pragma unroll
        for (int i4 = 0; i4 < 16; ++i4) {
            const float4 f = *(const float4*)&featL[wave][k * 68 + i4 * 4];
            acc = fmaf(f.x, wreg[i4 * 4 + 0], acc);
            acc = fmaf(f.y, wreg[i4 * 4 + 1], acc);
            acc = fmaf(f.z, wreg[i4 * 4 + 2], acc);
            acc = fmaf(f.w, wreg[i4 * 4 + 3], acc);
        }
        m = fmaxf(m, fmaxf(acc, 0.0f));
    }
    out[(size_t)c * HH + lane] = (cnt > 0) ? m : 0.0f;
}

extern "C" void kernel_launch(void* const* d_in, const int* in_sizes, int n_in,
                              void* d_out, int out_size, void* d_ws, size_t ws_size,
                              hipStream_t stream) {
    const float* x   = (const float*)d_in[0];
    const float* pos = (const float*)d_in[1];
    const float* W1  = (const float*)d_in[3];
    const float* b1  = (const float*)d_in[4];
    const float* W2  = (const float*)d_in[5];
    const float* b2  = (const float*)d_in[6];

    float* out         = (float*)d_out;
    float* centers_out = out + (size_t)NB * MM * HH;
    float* batch_out   = centers_out + (size_t)NB * MM * 3;

    char* ws = (char*)d_ws;
    int* samp   = (int*)ws;
    int* cntbuf = (int*)(ws + (size_t)NB * MM * 4);
    int* nbr    = (int*)(ws + (size_t)2 * NB * MM * 4);

    fps_kernel<<<NB, FT, 0, stream>>>(pos, samp, centers_out, batch_out);
    knn_kernel<<<(NB * MM) / 4, 256, 0, stream>>>(pos, samp, nbr, cntbuf);
    mlp_kernel<<<(NB * MM) / 4, 256, 0, stream>>>(x, pos, W1, b1, W2, b2,
                                                  nbr, cntbuf, centers_out, out);
}

// Round 17
// 2123.402 us; speedup vs baseline: 6.3991x; 1.1662x over previous
//
#include <hip/hip_runtime.h>
#include <hip/hip_bf16.h>
#include <float.h>
#include <math.h>

#define NB 4
#define NN 8192
#define FF 64
#define MM 2048
#define KK 32
#define HH 64

#define FT 512          // fps threads (8 waves)

typedef float v2f __attribute__((ext_vector_type(2)));

// DPP float-max step (old = -inf identity), validated r4/r11/r13.
#define DPP_FMAX(v, ctrl, rmask)                                                \
    { int _t = __builtin_amdgcn_update_dpp((int)0xff800000, __float_as_int(v),  \
                   (ctrl), (rmask), 0xf, false);                                \
      (v) = fmaxf((v), __int_as_float(_t)); }
#define DPP_FMAX6(v)  DPP_FMAX(v,0x111,0xf) DPP_FMAX(v,0x112,0xf) \
                      DPP_FMAX(v,0x114,0xf) DPP_FMAX(v,0x118,0xf) \
                      DPP_FMAX(v,0x142,0xa) DPP_FMAX(v,0x143,0xc)

// DPP int-min step (old = INT_MAX identity), validated r11/r13.
#define DPP_IMIN(v, ctrl, rmask)                                                \
    { int _t = __builtin_amdgcn_update_dpp((int)0x7fffffff, (v),                \
                   (ctrl), (rmask), 0xf, false);                                \
      (v) = min((v), _t); }
#define DPP_IMIN6(v)  DPP_IMIN(v,0x111,0xf) DPP_IMIN(v,0x112,0xf) \
                      DPP_IMIN(v,0x114,0xf) DPP_IMIN(v,0x118,0xf) \
                      DPP_IMIN(v,0x142,0xa) DPP_IMIN(v,0x143,0xc)

// ---------------- Kernel 1: exact FPS, two-phase value/index argmax (r11) ----------------
__global__ __launch_bounds__(FT) void fps_kernel(
    const float* __restrict__ pos,
    int* __restrict__ samp,
    float* __restrict__ centers_out,
    float* __restrict__ batch_out)
{
#pragma clang fp contract(off)
    __shared__ float4 pts4[NN];          // natural order; winner-fetch only (128 KB)
    __shared__ float vslot[2][8];        // parity per-wave value maxes
    __shared__ int   islot[2][8];        // parity per-wave min matching idx

    const int b = blockIdx.x;
    const float* pb = pos + (size_t)b * NN * 3;
    const int tid = threadIdx.x;
    const int w   = tid >> 6;
    const int lane = tid & 63;

    // ---- stage points; prefill batch ids ----
    for (int j = tid; j < NN; j += FT)
        pts4[j] = make_float4(pb[j * 3 + 0], pb[j * 3 + 1], pb[j * 3 + 2], 0.0f);
    for (int j = tid; j < MM; j += FT) batch_out[b * MM + j] = (float)b;
    __syncthreads();

    // ---- all 16 points in registers as 8 packed pairs ----
    // pair j: indices (2j)*FT+tid (.x) and (2j+1)*FT+tid (.y)
    v2f pxv[8], pyv[8], pzv[8], dv[8];
#pragma unroll
    for (int j = 0; j < 8; ++j) {
        const float4 p0 = pts4[(2 * j) * FT + tid];
        const float4 p1 = pts4[(2 * j + 1) * FT + tid];
        pxv[j] = (v2f){p0.x, p1.x};
        pyv[j] = (v2f){p0.y, p1.y};
        pzv[j] = (v2f){p0.z, p1.z};
        dv[j]  = (v2f){INFINITY, INFINITY};
    }

    int   cur = 0;
    float lx = pb[0], ly = pb[1], lz = pb[2];

    for (int s = 0; s < MM; ++s) {
#pragma clang fp contract(off)
        if (tid == 0) {
            samp[b * MM + s] = cur;
            centers_out[((size_t)b * MM + s) * 3 + 0] = lx;
            centers_out[((size_t)b * MM + s) * 3 + 1] = ly;
            centers_out[((size_t)b * MM + s) * 3 + 2] = lz;
        }
        if (s == MM - 1) break;   // last argmax unused by the reference

        const v2f l2x = (v2f){lx, lx};
        const v2f l2y = (v2f){ly, ly};
        const v2f l2z = (v2f){lz, lz};

        // ---- phase 1: distance update + VALUE-ONLY max (packed ops) ----
        v2f vmax2 = (v2f){-INFINITY, -INFINITY};
#pragma unroll
        for (int j = 0; j < 8; ++j) {
            const v2f dx = pxv[j] - l2x;
            const v2f dy = pyv[j] - l2y;
            const v2f dz = pzv[j] - l2z;
            const v2f d2 = (dx * dx + dy * dy) + dz * dz;   // exact: contract off
            dv[j] = __builtin_elementwise_min(dv[j], d2);   // jnp.minimum, exact
            vmax2 = __builtin_elementwise_max(vmax2, dv[j]);
        }
        const float tv = fmaxf(vmax2.x, vmax2.y);           // thread value max

        float wv = tv;
        DPP_FMAX6(wv)                                       // lane63: wave max
        const int par = s & 1;
        if (lane == 63) vslot[par][w] = wv;
        __syncthreads();

        const float4 v0 = *(const float4*)&vslot[par][0];
        const float4 v1 = *(const float4*)&vslot[par][4];
        const float V = fmaxf(fmaxf(fmaxf(v0.x, v0.y), fmaxf(v0.z, v0.w)),
                              fmaxf(fmaxf(v1.x, v1.y), fmaxf(v1.z, v1.w)));

        // ---- phase 2: rare index recovery (exec-sparse; usually 1 thread) ----
        int cand = 0x7fffffff;
        if (tv == V) {
            // scan stored dists for exact match; ascending index order ->
            // branchless min keeps the LOWEST matching index (ref tie-break)
#pragma unroll
            for (int j = 0; j < 8; ++j) {
                if (dv[j].x == V) cand = min(cand, (2 * j) * FT + tid);
                if (dv[j].y == V) cand = min(cand, (2 * j + 1) * FT + tid);
            }
        }
        DPP_IMIN6(cand)                                     // lane63: wave min idx
        if (lane == 63) islot[par][w] = cand;
        __syncthreads();

        const int4 i0 = *(const int4*)&islot[par][0];
        const int4 i1 = *(const int4*)&islot[par][4];
        cur = min(min(min(i0.x, i0.y), min(i0.z, i0.w)),
                  min(min(i1.x, i1.y), min(i1.z, i1.w)));

        const float4 wp = pts4[cur];                        // broadcast, conflict-free
        lx = wp.x; ly = wp.y; lz = wp.z;
    }
}

// ---------------- Kernel 2: radius-KNN, one wave per center ----------------
#define CAP 256
__global__ __launch_bounds__(256) void knn_kernel(
    const float* __restrict__ pos,
    const int* __restrict__ samp,
    int* __restrict__ nbr,
    int* __restrict__ cntbuf)
{
    const int wave = threadIdx.x >> 6;
    const int lane = threadIdx.x & 63;
    const int c = blockIdx.x * 4 + wave;
    const int b = c >> 11;
    const float* pb = pos + (size_t)b * NN * 3;

    __shared__ float sd2[4][CAP];
    __shared__ int   sid[4][CAP];

    const int ctr = samp[c];
    const float cx = pb[ctr * 3 + 0];
    const float cy = pb[ctr * 3 + 1];
    const float cz = pb[ctr * 3 + 2];
    const float R2 = (float)(0.1 * 0.1);

    int cnt = 0;
    for (int r = 0; r < NN / 64; ++r) {
        const int g = r * 64 + lane;
        float dx = __fsub_rn(cx, pb[g * 3 + 0]);
        float dy = __fsub_rn(cy, pb[g * 3 + 1]);
        float dz = __fsub_rn(cz, pb[g * 3 + 2]);
        float d2 = __fadd_rn(__fadd_rn(__fmul_rn(dx, dx), __fmul_rn(dy, dy)),
                             __fmul_rn(dz, dz));
        const bool pred = (d2 <= R2);
        const unsigned long long mask = __ballot(pred);
        const int before = __popcll(mask & ((1ull << lane) - 1ull));
        if (pred) {
            const int slot = cnt + before;
            if (slot < CAP) { sd2[wave][slot] = d2; sid[wave][slot] = g; }
        }
        cnt += __popcll(mask);
    }
    if (cnt > CAP) cnt = CAP;
    __syncthreads();

    for (int ci = lane; ci < cnt; ci += 64) {
        const float dc = sd2[wave][ci];
        const int   ic = sid[wave][ci];
        int rank = 0;
        for (int j = 0; j < cnt; ++j) {
            const float dj = sd2[wave][j];
            const int   ij = sid[wave][j];
            rank += (dj < dc || (dj == dc && ij < ic)) ? 1 : 0;
        }
        if (rank < KK) nbr[c * KK + rank] = ic;
    }
    if (lane == 0) cntbuf[c] = (cnt < KK) ? cnt : KK;
}

// ---------------- Kernel 3: gather + MLP + max-pool, one wave per center ----
__global__ __launch_bounds__(256) void mlp_kernel(
    const float* __restrict__ x,
    const float* __restrict__ pos,
    const float* __restrict__ W1,
    const float* __restrict__ b1,
    const float* __restrict__ W2,
    const float* __restrict__ b2,
    const int* __restrict__ nbr,
    const int* __restrict__ cntbuf,
    const float* __restrict__ centers,
    float* __restrict__ out)
{
    __shared__ float WT[64 * 68];
    __shared__ float featL[4][32 * 68];

    const int tid = threadIdx.x, wave = tid >> 6, lane = tid & 63;
    const int c = blockIdx.x * 4 + wave;
    const int b = c >> 11;
    const int cnt = cntbuf[c];

    for (int idx = tid; idx < 67 * 64; idx += 256) {
        const int i = idx >> 6, h = idx & 63;
        WT[h * 68 + i] = W1[idx];
    }
    if (tid < 64) WT[tid * 68 + 67] = 0.0f;

    const float ctr0 = centers[c * 3 + 0];
    const float ctr1 = centers[c * 3 + 1];
    const float ctr2 = centers[c * 3 + 2];
    for (int k = 0; k < cnt; ++k) {
        const int j = nbr[c * KK + k];
        featL[wave][k * 68 + lane] = x[((size_t)b * NN + j) * FF + lane];
        if (lane < 3) {
            const float pj = pos[((size_t)b * NN + j) * 3 + lane];
            const float ci = (lane == 0) ? ctr0 : ((lane == 1) ? ctr1 : ctr2);
            featL[wave][k * 68 + 64 + lane] = __fsub_rn(pj, ci);
        }
        if (lane == 3) featL[wave][k * 68 + 67] = 0.0f;
    }
    __syncthreads();

    float wreg[68];
#pragma unroll
    for (int i4 = 0; i4 < 17; ++i4) {
        const float4 v = *(const float4*)&WT[lane * 68 + i4 * 4];
        wreg[i4 * 4 + 0] = v.x; wreg[i4 * 4 + 1] = v.y;
        wreg[i4 * 4 + 2] = v.z; wreg[i4 * 4 + 3] = v.w;
    }
    const float bias1 = b1[lane];
    for (int k = 0; k < cnt; ++k) {
        float acc = bias1;
#pragma unroll
        for (int i4 = 0; i4 < 17; ++i4) {
            const float4 f = *(const float4*)&featL[wave][k * 68 + i4 * 4];
            acc = fmaf(f.x, wreg[i4 * 4 + 0], acc);
            acc = fmaf(f.y, wreg[i4 * 4 + 1], acc);
            acc = fmaf(f.z, wreg[i4 * 4 + 2], acc);
            acc = fmaf(f.w, wreg[i4 * 4 + 3], acc);
        }
        featL[wave][k * 68 + lane] = fmaxf(acc, 0.0f);
    }
    __syncthreads();

    for (int idx = tid; idx < 64 * 64; idx += 256) {
        const int i = idx >> 6, h = idx & 63;
        WT[h * 68 + i] = W2[idx];
    }
    __syncthreads();

#pragma unroll
    for (int i4 = 0; i4 < 16; ++i4) {
        const float4 v = *(const float4*)&WT[lane * 68 + i4 * 4];
        wreg[i4 * 4 + 0] = v.x; wreg[i4 * 4 + 1] = v.y;
        wreg[i4 * 4 + 2] = v.z; wreg[i4 * 4 + 3] = v.w;
    }
    const float bias2 = b2[lane];
    float m = -INFINITY;
    for (int k = 0; k < cnt; ++k) {
        float acc = bias2;
#pragma unroll
        for (int i4 = 0; i4 < 16; ++i4) {
            const float4 f = *(const float4*)&featL[wave][k * 68 + i4 * 4];
            acc = fmaf(f.x, wreg[i4 * 4 + 0], acc);
            acc = fmaf(f.y, wreg[i4 * 4 + 1], acc);
            acc = fmaf(f.z, wreg[i4 * 4 + 2], acc);
            acc = fmaf(f.w, wreg[i4 * 4 + 3], acc);
        }
        m = fmaxf(m, fmaxf(acc, 0.0f));
    }
    out[(size_t)c * HH + lane] = (cnt > 0) ? m : 0.0f;
}

extern "C" void kernel_launch(void* const* d_in, const int* in_sizes, int n_in,
                              void* d_out, int out_size, void* d_ws, size_t ws_size,
                              hipStream_t stream) {
    const float* x   = (const float*)d_in[0];
    const float* pos = (const float*)d_in[1];
    const float* W1  = (const float*)d_in[3];
    const float* b1  = (const float*)d_in[4];
    const float* W2  = (const float*)d_in[5];
    const float* b2  = (const float*)d_in[6];

    float* out         = (float*)d_out;
    float* centers_out = out + (size_t)NB * MM * HH;
    float* batch_out   = centers_out + (size_t)NB * MM * 3;

    char* ws = (char*)d_ws;
    int* samp   = (int*)ws;
    int* cntbuf = (int*)(ws + (size_t)NB * MM * 4);
    int* nbr    = (int*)(ws + (size_t)2 * NB * MM * 4);

    fps_kernel<<<NB, FT, 0, stream>>>(pos, samp, centers_out, batch_out);
    knn_kernel<<<(NB * MM) / 4, 256, 0, stream>>>(pos, samp, nbr, cntbuf);
    mlp_kernel<<<(NB * MM) / 4, 256, 0, stream>>>(x, pos, W1, b1, W2, b2,
                                                  nbr, cntbuf, centers_out, out);
}